// Round 12
// baseline (521.861 us; speedup 1.0000x reference)
//
#include <hip/hip_runtime.h>
#include <hip/hip_bf16.h>

// GRU scan with sparse resets. T=1024, B=256, D=128, H=128.
// Round 12: Phase 1: gi = seq @ Wi (f16 -> d_ws, pre-scaled 1/ln2 (r,z),
// 2/ln2 (n); bh_r/bh_z folded). Phase 2: BPB=1 MFMA scan, 256 blocks x
// 512 thr (8 waves = 2/SIMD). Wave w owns cols [w*16, w*16+16): 12 MFMA
// per wave (3 gates x 4 k-chunks); per-SIMD matrix-pipe time unchanged
// (2x12=24) but two waves interleave so ds_read/trans latencies overlap.
// Lane column cq = w*16+s for all q; roles: q0 -> ht writeback + final
// carry, q1 -> ys store. Zero-C MFMA inits; r/z before n; rst in LDS;
// BARL (lgkmcnt-only) barrier; gi prefetched 4 steps. Fallback if ws small.

#define T_STEPS 1024
#define B_SZ 256
#define D_SZ 128
#define H_SZ 128

#define SC_RZ 1.44269504f   // 1/ln2
#define SC_N  2.88539008f   // 2/ln2

typedef _Float16 h2 __attribute__((ext_vector_type(2)));
typedef _Float16 h8 __attribute__((ext_vector_type(8)));
typedef _Float16 f16x8 __attribute__((ext_vector_type(8)));
typedef float f32x4 __attribute__((ext_vector_type(4)));

union U8 { h8 v; h2 p[4]; };

__device__ __forceinline__ float dot2f(h2 a, h2 b, float c) {
#if __has_builtin(__builtin_amdgcn_fdot2)
  return __builtin_amdgcn_fdot2(a, b, c, false);
#else
  return c + (float)a.x * (float)b.x + (float)a.y * (float)b.y;
#endif
}

__device__ __forceinline__ float fastrcp(float x) {
#if __has_builtin(__builtin_amdgcn_rcpf)
  return __builtin_amdgcn_rcpf(x);
#else
  return 1.0f / x;
#endif
}

__device__ __forceinline__ float fexp2(float x) {
#if __has_builtin(__builtin_amdgcn_exp2f)
  return __builtin_amdgcn_exp2f(x);
#else
  return __builtin_exp2f(x);
#endif
}

// LDS-only barrier: don't drain vmcnt (ys stores / gi prefetch keep flowing)
#define BARL() asm volatile("s_waitcnt lgkmcnt(0)\n\ts_barrier" ::: "memory")

// ---- phase 1: gi[(t*B+b)*384] (f16) = scale*(seq @ Wi) + scaled bias(r,z) --
__global__ __launch_bounds__(256, 2)
void gi_gemm(const float* __restrict__ seq, const float* __restrict__ Wi,
             const float* __restrict__ bh, _Float16* __restrict__ gi) {
  const int tid = threadIdx.x;
  const int w = tid >> 6, lane = tid & 63;
  const int q = lane >> 4, s = lane & 15;

  f16x8 wF[6][4];
  float bcol[6];
#pragma unroll
  for (int j = 0; j < 6; j++) {
    const int col = w * 96 + j * 16 + s;
    const bool is_n = (w * 96 + j * 16) >= 256;
    const float sc = is_n ? SC_N : SC_RZ;
    bcol[j] = is_n ? 0.f : SC_RZ * bh[col];   // bh_n stays in the scan tail
#pragma unroll
    for (int kk = 0; kk < 4; kk++) {
      f16x8 f;
#pragma unroll
      for (int e = 0; e < 8; e++)
        f[e] = (_Float16)(sc * Wi[(size_t)(kk * 32 + q * 8 + e) * 384 + col]);
      wF[j][kk] = f;
    }
  }

  __shared__ __align__(16) _Float16 gis[16 * 384];
  const int NROWTILES = (T_STEPS * B_SZ) / 16;

  for (int r = blockIdx.x; r < NROWTILES; r += gridDim.x) {
    const float* xr = &seq[((size_t)r * 16 + s) * D_SZ];
    f16x8 af[4];
#pragma unroll
    for (int kk = 0; kk < 4; kk++) {
      float4 u0 = *(const float4*)(xr + kk * 32 + q * 8);
      float4 u1 = *(const float4*)(xr + kk * 32 + q * 8 + 4);
      f16x8 f;
      f[0] = (_Float16)u0.x; f[1] = (_Float16)u0.y;
      f[2] = (_Float16)u0.z; f[3] = (_Float16)u0.w;
      f[4] = (_Float16)u1.x; f[5] = (_Float16)u1.y;
      f[6] = (_Float16)u1.z; f[7] = (_Float16)u1.w;
      af[kk] = f;
    }
    f32x4 acc[6];
#pragma unroll
    for (int j = 0; j < 6; j++) acc[j] = (f32x4){0.f, 0.f, 0.f, 0.f};
#pragma unroll
    for (int kk = 0; kk < 4; kk++)
#pragma unroll
      for (int j = 0; j < 6; j++)
        acc[j] = __builtin_amdgcn_mfma_f32_16x16x32_f16(af[kk], wF[j][kk],
                                                        acc[j], 0, 0, 0);
#pragma unroll
    for (int j = 0; j < 6; j++) {
      const int col = w * 96 + j * 16 + s;
#pragma unroll
      for (int e = 0; e < 4; e++)
        gis[(q * 4 + e) * 384 + col] = (_Float16)(acc[j][e] + bcol[j]);
    }
    __syncthreads();
    const size_t base = (size_t)r * 16 * 384;
#pragma unroll
    for (int i = 0; i < 3; i++) {
      const int idx = tid + i * 256;
      *(float4*)(gi + base + (size_t)idx * 8) = *(const float4*)(gis + idx * 8);
    }
    __syncthreads();
  }
}

// ---------------- phase 2: BPB=1 MFMA scan, 8 waves ------------------------
struct Gi9 { _Float16 r, z, n; };   // gi values for THIS lane's column cq

#define GIL9(T_, G_) { \
    int tl_ = (T_); if (tl_ > T_STEPS - 1) tl_ = T_STEPS - 1; \
    const _Float16* gp_ = gib + (size_t)tl_ * (B_SZ * 384); \
    G_.r = gp_[0]; G_.z = gp_[128]; G_.n = gp_[256]; }

#define STEP9(T_, G_) { \
    const int p_ = (T_) & 1; \
    const int rn_ = rst[((T_) + 1) & (T_STEPS - 1)]; \
    f16x8 hf0_ = *(const f16x8*)&ht[p_][ 0 + q * 8]; \
    f16x8 hf1_ = *(const f16x8*)&ht[p_][32 + q * 8]; \
    f16x8 hf2_ = *(const f16x8*)&ht[p_][64 + q * 8]; \
    f16x8 hf3_ = *(const f16x8*)&ht[p_][96 + q * 8]; \
    const float gr_ = (float)G_.r, gz_ = (float)G_.z, gn_ = (float)G_.n; \
    GIL9((T_) + 4, G_) \
    /* r,z MFMAs first (zero-C inits), 2 independent chains */ \
    f32x4 aR_ = __builtin_amdgcn_mfma_f32_16x16x32_f16(hf0_, whF[0][0], Z4, 0, 0, 0); \
    f32x4 aZ_ = __builtin_amdgcn_mfma_f32_16x16x32_f16(hf0_, whF[1][0], Z4, 0, 0, 0); \
    aR_ = __builtin_amdgcn_mfma_f32_16x16x32_f16(hf1_, whF[0][1], aR_, 0, 0, 0); \
    aZ_ = __builtin_amdgcn_mfma_f32_16x16x32_f16(hf1_, whF[1][1], aZ_, 0, 0, 0); \
    aR_ = __builtin_amdgcn_mfma_f32_16x16x32_f16(hf2_, whF[0][2], aR_, 0, 0, 0); \
    aZ_ = __builtin_amdgcn_mfma_f32_16x16x32_f16(hf2_, whF[1][2], aZ_, 0, 0, 0); \
    aR_ = __builtin_amdgcn_mfma_f32_16x16x32_f16(hf3_, whF[0][3], aR_, 0, 0, 0); \
    aZ_ = __builtin_amdgcn_mfma_f32_16x16x32_f16(hf3_, whF[1][3], aZ_, 0, 0, 0); \
    /* n MFMAs; sigma(r),sigma(z) scheduled under their issue */ \
    f32x4 aN_ = __builtin_amdgcn_mfma_f32_16x16x32_f16(hf0_, whF[2][0], Z4, 0, 0, 0); \
    aN_ = __builtin_amdgcn_mfma_f32_16x16x32_f16(hf1_, whF[2][1], aN_, 0, 0, 0); \
    aN_ = __builtin_amdgcn_mfma_f32_16x16x32_f16(hf2_, whF[2][2], aN_, 0, 0, 0); \
    aN_ = __builtin_amdgcn_mfma_f32_16x16x32_f16(hf3_, whF[2][3], aN_, 0, 0, 0); \
    const float sR_ = aR_[0] + gr_; \
    const float sZ_ = aZ_[0] + gz_; \
    const float r_ = fastrcp(1.f + fexp2(-sR_)); \
    const float z_ = fastrcp(1.f + fexp2(-sZ_)); \
    const float sN_ = aN_[0] + bh_n; \
    const float e2_ = fexp2(gn_ + r_ * sN_); \
    const float n_ = 1.f - 2.f * fastrcp(e2_ + 1.f); \
    const float hnew_ = n_ + z_ * (hu - n_); \
    hu = rn_ ? h0c : hnew_; \
    yfin = hnew_; \
    if (q == 0) ht[p_ ^ 1][cq] = (_Float16)hu; \
    else if (q == 1) ys[((size_t)(T_) * B_SZ + b) * H_SZ + cq] = hnew_; \
    BARL(); }

__global__ __launch_bounds__(512, 2)
void gru_scan9(const _Float16* __restrict__ gi,
               const int* __restrict__ resets,
               const float* __restrict__ h0,
               const float* __restrict__ Wh,
               const float* __restrict__ bh,
               float* __restrict__ out) {
  const int b = blockIdx.x;
  const int tid = threadIdx.x;
  const int w = tid >> 6;          // wave 0..7: cols [w*16, w*16+16)
  const int lane = tid & 63;
  const int q = lane >> 4;         // A k-group / role group
  const int s = lane & 15;         // B/C col within tile
  const int cq = w * 16 + s;       // this lane's column

  __shared__ int rst[T_STEPS];                      // 4 KB
  __shared__ __align__(16) _Float16 ht[2][H_SZ];    // 512 B, linear

  for (int i = tid; i < T_STEPS; i += 512)
    rst[i] = resets[(size_t)i * B_SZ + b];

  // Wh B-frags (pre-scaled): gate g3 -> col g3*128 + cq; k = kk*32 + q*8 + e
  f16x8 whF[3][4];
#pragma unroll
  for (int g3 = 0; g3 < 3; g3++) {
    const float sc = (g3 == 2) ? SC_N : SC_RZ;
    const int col = g3 * H_SZ + cq;
#pragma unroll
    for (int kk = 0; kk < 4; kk++) {
      f16x8 f;
#pragma unroll
      for (int e = 0; e < 8; e++)
        f[e] = (_Float16)(sc * Wh[(size_t)(kk * 32 + q * 8 + e) * 384 + col]);
      whF[g3][kk] = f;
    }
  }

  const f32x4 Z4 = {0.f, 0.f, 0.f, 0.f};
  const float bh_n = SC_N * bh[2 * H_SZ + cq];
  const float h0c = h0[(size_t)b * H_SZ + cq];
  float hu = h0c;
  float yfin = h0c;

  if (tid < H_SZ) ht[0][tid] = (_Float16)h0[(size_t)b * H_SZ + tid];

  const _Float16* gib = gi + (size_t)b * 384 + cq;
  Gi9 gA, gB, gC, gD;
  GIL9(0, gA)
  GIL9(1, gB)
  GIL9(2, gC)
  GIL9(3, gD)
  __syncthreads();

  float* ys = out + (size_t)B_SZ * H_SZ;  // out = [final_carry] ++ [ys]

#pragma unroll 1
  for (int t = 0; t < T_STEPS; t += 8) {
    STEP9(t + 0, gA)
    STEP9(t + 1, gB)
    STEP9(t + 2, gC)
    STEP9(t + 3, gD)
    STEP9(t + 4, gA)
    STEP9(t + 5, gB)
    STEP9(t + 6, gC)
    STEP9(t + 7, gD)
  }
  if (q == 0) out[(size_t)b * H_SZ + cq] = yfin;  // final carry = hnew(1023)
}

// ---------------- fallback: fused single-kernel (ws too small) ------------
__global__ __launch_bounds__(512, 2)
void gru_scan_fb(const float* __restrict__ seq,
                 const int* __restrict__ resets,
                 const float* __restrict__ h0,
                 const float* __restrict__ Wi,
                 const float* __restrict__ Wh,
                 const float* __restrict__ bh,
                 float* __restrict__ out) {
  const int b = blockIdx.x;
  const int tid = threadIdx.x;
  const int w = tid >> 6;
  const int lane = tid & 63;
  const int c = (w << 4) | (lane & 15);
  const int g = lane >> 4;

  __shared__ int rst[T_STEPS];
  __shared__ __align__(16) _Float16 x16[2][D_SZ];
  __shared__ __align__(16) _Float16 hh16[2][H_SZ];

  for (int i = tid; i < T_STEPS; i += 512) rst[i] = resets[(size_t)i * B_SZ + b];

  h2 wiR[3][16], whR[3][16];
  const int k0 = g * 32;
#pragma unroll
  for (int ch = 0; ch < 3; ch++) {
    const int col = ch * H_SZ + c;
#pragma unroll
    for (int j = 0; j < 16; j++) {
      const int k = k0 + 2 * j;
      h2 wa; wa.x = (_Float16)Wi[(size_t)k * 384 + col];
             wa.y = (_Float16)Wi[(size_t)(k + 1) * 384 + col];
      wiR[ch][j] = wa;
      h2 wb; wb.x = (_Float16)Wh[(size_t)k * 384 + col];
             wb.y = (_Float16)Wh[(size_t)(k + 1) * 384 + col];
      whR[ch][j] = wb;
    }
  }

  const float bhr = bh[c], bhz = bh[H_SZ + c], bhn = bh[2 * H_SZ + c];
  const float h0c = h0[(size_t)b * H_SZ + c];
  float hu = h0c;

  if (tid < H_SZ) {
    hh16[0][tid] = (_Float16)h0[(size_t)b * H_SZ + tid];
    x16[0][tid]  = (_Float16)seq[((size_t)0 * B_SZ + b) * D_SZ + tid];
  }
  float xA = 0.f, xB = 0.f;
  if (tid < D_SZ) {
    xA = seq[((size_t)1 * B_SZ + b) * D_SZ + tid];
    xB = seq[((size_t)2 * B_SZ + b) * D_SZ + tid];
  }
  __syncthreads();

  float* ys = out + (size_t)B_SZ * H_SZ;

#pragma unroll 1
  for (int t = 0; t < T_STEPS; t++) {
    const int p = t & 1;
    const int rnext = rst[(t + 1) & (T_STEPS - 1)];

    const h8* xb = (const h8*)&x16[p][g * 32];
    const h8* hb = (const h8*)&hh16[p][g * 32];
    float cr = 0.f, cz = 0.f, ci = 0.f, chn = 0.f;
#pragma unroll
    for (int qq = 0; qq < 4; qq++) {
      U8 ux, uh; ux.v = xb[qq]; uh.v = hb[qq];
#pragma unroll
      for (int j = 0; j < 4; j++) {
        const int idx = qq * 4 + j;
        cr  = dot2f(ux.p[j], wiR[0][idx], cr);
        cz  = dot2f(ux.p[j], wiR[1][idx], cz);
        ci  = dot2f(ux.p[j], wiR[2][idx], ci);
        cr  = dot2f(uh.p[j], whR[0][idx], cr);
        cz  = dot2f(uh.p[j], whR[1][idx], cz);
        chn = dot2f(uh.p[j], whR[2][idx], chn);
      }
    }
    cr  += __shfl_xor(cr, 16, 64);
    cz  += __shfl_xor(cz, 16, 64);
    ci  += __shfl_xor(ci, 16, 64);
    chn += __shfl_xor(chn, 16, 64);
    cr  += __shfl_xor(cr, 32, 64);
    cz  += __shfl_xor(cz, 32, 64);
    ci  += __shfl_xor(ci, 32, 64);
    chn += __shfl_xor(chn, 32, 64);

    const float ar = cr + bhr;
    const float az = cz + bhz;
    const float ah = chn + bhn;
    const float r = fastrcp(1.f + __expf(-ar));
    const float z = fastrcp(1.f + __expf(-az));
    const float ta = ci + r * ah;
    const float e2 = __expf(2.f * ta);
    const float n = 1.f - 2.f * fastrcp(e2 + 1.f);
    const float hnew = n + z * (hu - n);
    const float hunew = rnext ? h0c : hnew;
    hu = hunew;

    if (g == 0) {
      ys[((size_t)t * B_SZ + b) * H_SZ + c] = hnew;
      hh16[p ^ 1][c] = (_Float16)hunew;
      if (t == T_STEPS - 1) out[(size_t)b * H_SZ + c] = hnew;
    }
    if (tid < D_SZ) {
      x16[p ^ 1][tid] = (_Float16)xA;
      xA = xB;
      int tt = t + 3; if (tt > T_STEPS - 1) tt = T_STEPS - 1;
      xB = seq[((size_t)tt * B_SZ + b) * D_SZ + tid];
    }
    __syncthreads();
  }
}

extern "C" void kernel_launch(void* const* d_in, const int* in_sizes, int n_in,
                              void* d_out, int out_size, void* d_ws, size_t ws_size,
                              hipStream_t stream) {
  const float* seq    = (const float*)d_in[0];
  const int*   resets = (const int*)d_in[1];
  const float* h0     = (const float*)d_in[2];
  const float* Wi     = (const float*)d_in[3];
  const float* Wh     = (const float*)d_in[4];
  const float* bh     = (const float*)d_in[5];
  (void)in_sizes; (void)n_in; (void)out_size;

  const size_t need = (size_t)T_STEPS * B_SZ * 384 * sizeof(_Float16);
  if (ws_size >= need && d_ws != nullptr) {
    _Float16* gi = (_Float16*)d_ws;
    gi_gemm<<<1024, 256, 0, stream>>>(seq, Wi, bh, gi);
    gru_scan9<<<B_SZ, 512, 0, stream>>>(gi, resets, h0, Wh, bh, (float*)d_out);
  } else {
    gru_scan_fb<<<B_SZ, 512, 0, stream>>>(seq, resets, h0, Wi, Wh, bh,
                                          (float*)d_out);
  }
}

// Round 13
// 495.066 us; speedup vs baseline: 1.0541x; 1.0541x over previous
//
#include <hip/hip_runtime.h>
#include <hip/hip_bf16.h>

// GRU scan with sparse resets. T=1024, B=256, D=128, H=128.
// Round 13: scan8 structure (best: 419us) + schedule polish.
// Phase 1: gi = seq @ Wi (f16 -> d_ws, pre-scaled 1/ln2 (r,z), 2/ln2 (n);
// bh_r/bh_z folded). Phase 2: BPB=1 MFMA scan, 256 blocks x 256 thr
// (4 waves, 1/SIMD). Per wave 24 MFMA as THREE dependent per-gate chains
// r -> z -> n (cg0/cg1 interleaved): aR retires ~slot 8, aZ ~slot 16, so
// sigma(r)/sigma(z) run on the VALU under the n-MFMA issue window; only
// the short e2 chain remains after the last MFMA. rst flags SHIFTED by 1
// in LDS and read as 2x int4 per 8-step block (off-chain, in registers).
// Zero-C inits; q-split roles (q&1: ht writeback vs ys store); BARL
// (lgkmcnt-only) barrier; gi prefetched 4 steps. Fallback if ws small.

#define T_STEPS 1024
#define B_SZ 256
#define D_SZ 128
#define H_SZ 128

#define SC_RZ 1.44269504f   // 1/ln2
#define SC_N  2.88539008f   // 2/ln2

typedef _Float16 h2 __attribute__((ext_vector_type(2)));
typedef _Float16 h8 __attribute__((ext_vector_type(8)));
typedef _Float16 f16x8 __attribute__((ext_vector_type(8)));
typedef float f32x4 __attribute__((ext_vector_type(4)));

union U8 { h8 v; h2 p[4]; };

__device__ __forceinline__ float dot2f(h2 a, h2 b, float c) {
#if __has_builtin(__builtin_amdgcn_fdot2)
  return __builtin_amdgcn_fdot2(a, b, c, false);
#else
  return c + (float)a.x * (float)b.x + (float)a.y * (float)b.y;
#endif
}

__device__ __forceinline__ float fastrcp(float x) {
#if __has_builtin(__builtin_amdgcn_rcpf)
  return __builtin_amdgcn_rcpf(x);
#else
  return 1.0f / x;
#endif
}

__device__ __forceinline__ float fexp2(float x) {
#if __has_builtin(__builtin_amdgcn_exp2f)
  return __builtin_amdgcn_exp2f(x);
#else
  return __builtin_exp2f(x);
#endif
}

// LDS-only barrier: don't drain vmcnt (ys stores / gi prefetch keep flowing)
#define BARL() asm volatile("s_waitcnt lgkmcnt(0)\n\ts_barrier" ::: "memory")

// ---- phase 1: gi[(t*B+b)*384] (f16) = scale*(seq @ Wi) + scaled bias(r,z) --
__global__ __launch_bounds__(256, 2)
void gi_gemm(const float* __restrict__ seq, const float* __restrict__ Wi,
             const float* __restrict__ bh, _Float16* __restrict__ gi) {
  const int tid = threadIdx.x;
  const int w = tid >> 6, lane = tid & 63;
  const int q = lane >> 4, s = lane & 15;

  f16x8 wF[6][4];
  float bcol[6];
#pragma unroll
  for (int j = 0; j < 6; j++) {
    const int col = w * 96 + j * 16 + s;
    const bool is_n = (w * 96 + j * 16) >= 256;
    const float sc = is_n ? SC_N : SC_RZ;
    bcol[j] = is_n ? 0.f : SC_RZ * bh[col];   // bh_n stays in the scan tail
#pragma unroll
    for (int kk = 0; kk < 4; kk++) {
      f16x8 f;
#pragma unroll
      for (int e = 0; e < 8; e++)
        f[e] = (_Float16)(sc * Wi[(size_t)(kk * 32 + q * 8 + e) * 384 + col]);
      wF[j][kk] = f;
    }
  }

  __shared__ __align__(16) _Float16 gis[16 * 384];
  const int NROWTILES = (T_STEPS * B_SZ) / 16;

  for (int r = blockIdx.x; r < NROWTILES; r += gridDim.x) {
    const float* xr = &seq[((size_t)r * 16 + s) * D_SZ];
    f16x8 af[4];
#pragma unroll
    for (int kk = 0; kk < 4; kk++) {
      float4 u0 = *(const float4*)(xr + kk * 32 + q * 8);
      float4 u1 = *(const float4*)(xr + kk * 32 + q * 8 + 4);
      f16x8 f;
      f[0] = (_Float16)u0.x; f[1] = (_Float16)u0.y;
      f[2] = (_Float16)u0.z; f[3] = (_Float16)u0.w;
      f[4] = (_Float16)u1.x; f[5] = (_Float16)u1.y;
      f[6] = (_Float16)u1.z; f[7] = (_Float16)u1.w;
      af[kk] = f;
    }
    f32x4 acc[6];
#pragma unroll
    for (int j = 0; j < 6; j++) acc[j] = (f32x4){0.f, 0.f, 0.f, 0.f};
#pragma unroll
    for (int kk = 0; kk < 4; kk++)
#pragma unroll
      for (int j = 0; j < 6; j++)
        acc[j] = __builtin_amdgcn_mfma_f32_16x16x32_f16(af[kk], wF[j][kk],
                                                        acc[j], 0, 0, 0);
#pragma unroll
    for (int j = 0; j < 6; j++) {
      const int col = w * 96 + j * 16 + s;
#pragma unroll
      for (int e = 0; e < 4; e++)
        gis[(q * 4 + e) * 384 + col] = (_Float16)(acc[j][e] + bcol[j]);
    }
    __syncthreads();
    const size_t base = (size_t)r * 16 * 384;
#pragma unroll
    for (int i = 0; i < 3; i++) {
      const int idx = tid + i * 256;
      *(float4*)(gi + base + (size_t)idx * 8) = *(const float4*)(gis + idx * 8);
    }
    __syncthreads();
  }
}

// ---------------- phase 2: BPB=1 MFMA scan, polished schedule --------------
struct GiX { _Float16 r, z, n; };   // gi values for THIS lane's column cq

#define GILX(T_, G_) { \
    int tl_ = (T_); if (tl_ > T_STEPS - 1) tl_ = T_STEPS - 1; \
    const _Float16* gp_ = gib + (size_t)tl_ * (B_SZ * 384); \
    G_.r = gp_[0]; G_.z = gp_[128]; G_.n = gp_[256]; }

#define STEPX(T_, G_, RN_) { \
    const int p_ = (T_) & 1; \
    f16x8 hf0_ = *(const f16x8*)&ht[p_][ 0 + q * 8]; \
    f16x8 hf1_ = *(const f16x8*)&ht[p_][32 + q * 8]; \
    f16x8 hf2_ = *(const f16x8*)&ht[p_][64 + q * 8]; \
    f16x8 hf3_ = *(const f16x8*)&ht[p_][96 + q * 8]; \
    const float gr_ = (float)G_.r, gz_ = (float)G_.z, gn_ = (float)G_.n; \
    GILX((T_) + 4, G_) \
    /* r chains first (retire earliest), then z, then n */ \
    f32x4 aR0_ = __builtin_amdgcn_mfma_f32_16x16x32_f16(hf0_, whF[0][0][0], Z4, 0, 0, 0); \
    f32x4 aR1_ = __builtin_amdgcn_mfma_f32_16x16x32_f16(hf0_, whF[0][1][0], Z4, 0, 0, 0); \
    aR0_ = __builtin_amdgcn_mfma_f32_16x16x32_f16(hf1_, whF[0][0][1], aR0_, 0, 0, 0); \
    aR1_ = __builtin_amdgcn_mfma_f32_16x16x32_f16(hf1_, whF[0][1][1], aR1_, 0, 0, 0); \
    aR0_ = __builtin_amdgcn_mfma_f32_16x16x32_f16(hf2_, whF[0][0][2], aR0_, 0, 0, 0); \
    aR1_ = __builtin_amdgcn_mfma_f32_16x16x32_f16(hf2_, whF[0][1][2], aR1_, 0, 0, 0); \
    aR0_ = __builtin_amdgcn_mfma_f32_16x16x32_f16(hf3_, whF[0][0][3], aR0_, 0, 0, 0); \
    aR1_ = __builtin_amdgcn_mfma_f32_16x16x32_f16(hf3_, whF[0][1][3], aR1_, 0, 0, 0); \
    f32x4 aZ0_ = __builtin_amdgcn_mfma_f32_16x16x32_f16(hf0_, whF[1][0][0], Z4, 0, 0, 0); \
    f32x4 aZ1_ = __builtin_amdgcn_mfma_f32_16x16x32_f16(hf0_, whF[1][1][0], Z4, 0, 0, 0); \
    aZ0_ = __builtin_amdgcn_mfma_f32_16x16x32_f16(hf1_, whF[1][0][1], aZ0_, 0, 0, 0); \
    aZ1_ = __builtin_amdgcn_mfma_f32_16x16x32_f16(hf1_, whF[1][1][1], aZ1_, 0, 0, 0); \
    aZ0_ = __builtin_amdgcn_mfma_f32_16x16x32_f16(hf2_, whF[1][0][2], aZ0_, 0, 0, 0); \
    aZ1_ = __builtin_amdgcn_mfma_f32_16x16x32_f16(hf2_, whF[1][1][2], aZ1_, 0, 0, 0); \
    aZ0_ = __builtin_amdgcn_mfma_f32_16x16x32_f16(hf3_, whF[1][0][3], aZ0_, 0, 0, 0); \
    aZ1_ = __builtin_amdgcn_mfma_f32_16x16x32_f16(hf3_, whF[1][1][3], aZ1_, 0, 0, 0); \
    f32x4 aN0_ = __builtin_amdgcn_mfma_f32_16x16x32_f16(hf0_, whF[2][0][0], Z4, 0, 0, 0); \
    f32x4 aN1_ = __builtin_amdgcn_mfma_f32_16x16x32_f16(hf0_, whF[2][1][0], Z4, 0, 0, 0); \
    aN0_ = __builtin_amdgcn_mfma_f32_16x16x32_f16(hf1_, whF[2][0][1], aN0_, 0, 0, 0); \
    aN1_ = __builtin_amdgcn_mfma_f32_16x16x32_f16(hf1_, whF[2][1][1], aN1_, 0, 0, 0); \
    aN0_ = __builtin_amdgcn_mfma_f32_16x16x32_f16(hf2_, whF[2][0][2], aN0_, 0, 0, 0); \
    aN1_ = __builtin_amdgcn_mfma_f32_16x16x32_f16(hf2_, whF[2][1][2], aN1_, 0, 0, 0); \
    aN0_ = __builtin_amdgcn_mfma_f32_16x16x32_f16(hf3_, whF[2][0][3], aN0_, 0, 0, 0); \
    aN1_ = __builtin_amdgcn_mfma_f32_16x16x32_f16(hf3_, whF[2][1][3], aN1_, 0, 0, 0); \
    /* tail: r,z sigmas overlap n-issue (aR/aZ retired early) */ \
    const float sR_ = (cg ? aR1_[0] : aR0_[0]) + gr_; \
    const float r_ = fastrcp(1.f + fexp2(-sR_)); \
    const float sZ_ = (cg ? aZ1_[0] : aZ0_[0]) + gz_; \
    const float z_ = fastrcp(1.f + fexp2(-sZ_)); \
    const float sN_ = (cg ? aN1_[0] : aN0_[0]) + bh_n; \
    const float e2_ = fexp2(gn_ + r_ * sN_); \
    const float n_ = 1.f - 2.f * fastrcp(e2_ + 1.f); \
    const float hnew_ = n_ + z_ * (hu - n_); \
    hu = (RN_) ? h0c : hnew_; \
    if (wrH) ht[p_ ^ 1][cq] = (_Float16)hu; \
    else ys[((size_t)(T_) * B_SZ + b) * H_SZ + cq] = hnew_; \
    yfin = hnew_; \
    BARL(); }

__global__ __launch_bounds__(256, 1)
void gru_scan10(const _Float16* __restrict__ gi,
                const int* __restrict__ resets,
                const float* __restrict__ h0,
                const float* __restrict__ Wh,
                const float* __restrict__ bh,
                float* __restrict__ out) {
  const int b = blockIdx.x;
  const int tid = threadIdx.x;
  const int w = tid >> 6;          // wave 0..3: cols [w*32, w*32+32)
  const int lane = tid & 63;
  const int q = lane >> 4;         // A k-group / role group
  const int s = lane & 15;         // B/C col within tile
  const int cg = q >> 1;           // which 16-col tile this lane owns
  const int cq = w * 32 + (cg << 4) + s;  // this lane's column
  const bool wrH = ((q & 1) == 0); // role: h-writeback vs ys store

  __shared__ int rsts[T_STEPS];                     // 4 KB, SHIFTED by 1
  __shared__ __align__(16) _Float16 ht[2][H_SZ];    // 512 B, linear

  for (int i = tid; i < T_STEPS; i += 256)
    rsts[i] = (i < T_STEPS - 1) ? resets[(size_t)(i + 1) * B_SZ + b] : 0;

  // Wh B-frags (pre-scaled): gate g3, coltile c2 -> col g3*128 + w*32 +
  // c2*16 + s; k = kk*32 + q*8 + e.
  f16x8 whF[3][2][4];
#pragma unroll
  for (int g3 = 0; g3 < 3; g3++) {
    const float sc = (g3 == 2) ? SC_N : SC_RZ;
#pragma unroll
    for (int c2 = 0; c2 < 2; c2++) {
      const int col = g3 * H_SZ + w * 32 + c2 * 16 + s;
#pragma unroll
      for (int kk = 0; kk < 4; kk++) {
        f16x8 f;
#pragma unroll
        for (int e = 0; e < 8; e++)
          f[e] = (_Float16)(sc * Wh[(size_t)(kk * 32 + q * 8 + e) * 384 + col]);
        whF[g3][c2][kk] = f;
      }
    }
  }

  const f32x4 Z4 = {0.f, 0.f, 0.f, 0.f};
  const float bh_n = SC_N * bh[2 * H_SZ + cq];
  const float h0c = h0[(size_t)b * H_SZ + cq];
  float hu = h0c;
  float yfin = h0c;

  if (tid < H_SZ) ht[0][tid] = (_Float16)h0[(size_t)b * H_SZ + tid];

  const _Float16* gib = gi + (size_t)b * 384 + cq;
  GiX gA, gB, gC, gD;
  GILX(0, gA)
  GILX(1, gB)
  GILX(2, gC)
  GILX(3, gD)
  __syncthreads();

  float* ys = out + (size_t)B_SZ * H_SZ;  // out = [final_carry] ++ [ys]

#pragma unroll 1
  for (int t = 0; t < T_STEPS; t += 8) {
    const int4 ra = *(const int4*)&rsts[t];      // flags for steps t..t+3
    const int4 rb = *(const int4*)&rsts[t + 4];  // flags for steps t+4..t+7
    STEPX(t + 0, gA, ra.x)
    STEPX(t + 1, gB, ra.y)
    STEPX(t + 2, gC, ra.z)
    STEPX(t + 3, gD, ra.w)
    STEPX(t + 4, gA, rb.x)
    STEPX(t + 5, gB, rb.y)
    STEPX(t + 6, gC, rb.z)
    STEPX(t + 7, gD, rb.w)
  }
  if (wrH) out[(size_t)b * H_SZ + cq] = yfin;  // final carry = hnew(1023)
}

// ---------------- fallback: fused single-kernel (ws too small) ------------
__global__ __launch_bounds__(512, 2)
void gru_scan_fb(const float* __restrict__ seq,
                 const int* __restrict__ resets,
                 const float* __restrict__ h0,
                 const float* __restrict__ Wi,
                 const float* __restrict__ Wh,
                 const float* __restrict__ bh,
                 float* __restrict__ out) {
  const int b = blockIdx.x;
  const int tid = threadIdx.x;
  const int w = tid >> 6;
  const int lane = tid & 63;
  const int c = (w << 4) | (lane & 15);
  const int g = lane >> 4;

  __shared__ int rst[T_STEPS];
  __shared__ __align__(16) _Float16 x16[2][D_SZ];
  __shared__ __align__(16) _Float16 hh16[2][H_SZ];

  for (int i = tid; i < T_STEPS; i += 512) rst[i] = resets[(size_t)i * B_SZ + b];

  h2 wiR[3][16], whR[3][16];
  const int k0 = g * 32;
#pragma unroll
  for (int ch = 0; ch < 3; ch++) {
    const int col = ch * H_SZ + c;
#pragma unroll
    for (int j = 0; j < 16; j++) {
      const int k = k0 + 2 * j;
      h2 wa; wa.x = (_Float16)Wi[(size_t)k * 384 + col];
             wa.y = (_Float16)Wi[(size_t)(k + 1) * 384 + col];
      wiR[ch][j] = wa;
      h2 wb; wb.x = (_Float16)Wh[(size_t)k * 384 + col];
             wb.y = (_Float16)Wh[(size_t)(k + 1) * 384 + col];
      whR[ch][j] = wb;
    }
  }

  const float bhr = bh[c], bhz = bh[H_SZ + c], bhn = bh[2 * H_SZ + c];
  const float h0c = h0[(size_t)b * H_SZ + c];
  float hu = h0c;

  if (tid < H_SZ) {
    hh16[0][tid] = (_Float16)h0[(size_t)b * H_SZ + tid];
    x16[0][tid]  = (_Float16)seq[((size_t)0 * B_SZ + b) * D_SZ + tid];
  }
  float xA = 0.f, xB = 0.f;
  if (tid < D_SZ) {
    xA = seq[((size_t)1 * B_SZ + b) * D_SZ + tid];
    xB = seq[((size_t)2 * B_SZ + b) * D_SZ + tid];
  }
  __syncthreads();

  float* ys = out + (size_t)B_SZ * H_SZ;

#pragma unroll 1
  for (int t = 0; t < T_STEPS; t++) {
    const int p = t & 1;
    const int rnext = rst[(t + 1) & (T_STEPS - 1)];

    const h8* xb = (const h8*)&x16[p][g * 32];
    const h8* hb = (const h8*)&hh16[p][g * 32];
    float cr = 0.f, cz = 0.f, ci = 0.f, chn = 0.f;
#pragma unroll
    for (int qq = 0; qq < 4; qq++) {
      U8 ux, uh; ux.v = xb[qq]; uh.v = hb[qq];
#pragma unroll
      for (int j = 0; j < 4; j++) {
        const int idx = qq * 4 + j;
        cr  = dot2f(ux.p[j], wiR[0][idx], cr);
        cz  = dot2f(ux.p[j], wiR[1][idx], cz);
        ci  = dot2f(ux.p[j], wiR[2][idx], ci);
        cr  = dot2f(uh.p[j], whR[0][idx], cr);
        cz  = dot2f(uh.p[j], whR[1][idx], cz);
        chn = dot2f(uh.p[j], whR[2][idx], chn);
      }
    }
    cr  += __shfl_xor(cr, 16, 64);
    cz  += __shfl_xor(cz, 16, 64);
    ci  += __shfl_xor(ci, 16, 64);
    chn += __shfl_xor(chn, 16, 64);
    cr  += __shfl_xor(cr, 32, 64);
    cz  += __shfl_xor(cz, 32, 64);
    ci  += __shfl_xor(ci, 32, 64);
    chn += __shfl_xor(chn, 32, 64);

    const float ar = cr + bhr;
    const float az = cz + bhz;
    const float ah = chn + bhn;
    const float r = fastrcp(1.f + __expf(-ar));
    const float z = fastrcp(1.f + __expf(-az));
    const float ta = ci + r * ah;
    const float e2 = __expf(2.f * ta);
    const float n = 1.f - 2.f * fastrcp(e2 + 1.f);
    const float hnew = n + z * (hu - n);
    const float hunew = rnext ? h0c : hnew;
    hu = hunew;

    if (g == 0) {
      ys[((size_t)t * B_SZ + b) * H_SZ + c] = hnew;
      hh16[p ^ 1][c] = (_Float16)hunew;
      if (t == T_STEPS - 1) out[(size_t)b * H_SZ + c] = hnew;
    }
    if (tid < D_SZ) {
      x16[p ^ 1][tid] = (_Float16)xA;
      xA = xB;
      int tt = t + 3; if (tt > T_STEPS - 1) tt = T_STEPS - 1;
      xB = seq[((size_t)tt * B_SZ + b) * D_SZ + tid];
    }
    __syncthreads();
  }
}

extern "C" void kernel_launch(void* const* d_in, const int* in_sizes, int n_in,
                              void* d_out, int out_size, void* d_ws, size_t ws_size,
                              hipStream_t stream) {
  const float* seq    = (const float*)d_in[0];
  const int*   resets = (const int*)d_in[1];
  const float* h0     = (const float*)d_in[2];
  const float* Wi     = (const float*)d_in[3];
  const float* Wh     = (const float*)d_in[4];
  const float* bh     = (const float*)d_in[5];
  (void)in_sizes; (void)n_in; (void)out_size;

  const size_t need = (size_t)T_STEPS * B_SZ * 384 * sizeof(_Float16);
  if (ws_size >= need && d_ws != nullptr) {
    _Float16* gi = (_Float16*)d_ws;
    gi_gemm<<<1024, 256, 0, stream>>>(seq, Wi, bh, gi);
    gru_scan10<<<B_SZ, 256, 0, stream>>>(gi, resets, h0, Wh, bh, (float*)d_out);
  } else {
    gru_scan_fb<<<B_SZ, 512, 0, stream>>>(seq, resets, h0, Wi, Wh, bh,
                                          (float*)d_out);
  }
}

// Round 14
// 372.576 us; speedup vs baseline: 1.4007x; 1.3288x over previous
//
#include <hip/hip_runtime.h>
#include <hip/hip_bf16.h>

// GRU scan with sparse resets. T=1024, B=256, D=128, H=128.
// Round 14: SINGLE fused kernel. The 16 MFMA A-rows (wasted on replicated h)
// are used once per 16 steps to compute gi = x[T0+16..T0+31] @ Wi for the
// NEXT 16-step block (24 MFMA/wave per 16 steps = +1.5/step amortized),
// double-buffered in LDS as packed {r,z,n,pad} f16x4 per (row,col).
// This deletes the separate gi_gemm dispatch (75us) and its 201MB HBM
// round-trip. Step path = scan10 (best, 944 cyc/step): 256 blocks x 256 thr
// (4 waves, 1/SIMD), 24 MFMA r->z->n dependent chains, zero-C inits,
// q-split roles, rst shifted in LDS read as int4, BARL lgkmcnt-only
// barrier. gi consume = one ds_read_b64, prefetched 4 steps ahead with
// compile-time row/parity. x loaded 16 steps ahead (fire-and-forget).

#define T_STEPS 1024
#define B_SZ 256
#define D_SZ 128
#define H_SZ 128

#define SC_RZ 1.44269504f   // 1/ln2
#define SC_N  2.88539008f   // 2/ln2

typedef _Float16 f16x4 __attribute__((ext_vector_type(4)));
typedef _Float16 f16x8 __attribute__((ext_vector_type(8)));
typedef float f32x4 __attribute__((ext_vector_type(4)));

__device__ __forceinline__ float fastrcp(float x) {
#if __has_builtin(__builtin_amdgcn_rcpf)
  return __builtin_amdgcn_rcpf(x);
#else
  return 1.0f / x;
#endif
}

__device__ __forceinline__ float fexp2(float x) {
#if __has_builtin(__builtin_amdgcn_exp2f)
  return __builtin_amdgcn_exp2f(x);
#else
  return __builtin_exp2f(x);
#endif
}

// LDS-only barrier: don't drain vmcnt (ys stores / x prefetch keep flowing)
#define BARL() asm volatile("s_waitcnt lgkmcnt(0)\n\ts_barrier" ::: "memory")

// issue 8 float4 loads of x[TT + s] k-slice q*8.. (fire & forget, 16-step lead)
#define LOADX(TT_, Y_) { \
    int tl_ = (TT_) + s; if (tl_ > T_STEPS - 1) tl_ = T_STEPS - 1; \
    const float* xp_ = &seq[((size_t)tl_ * B_SZ + b) * D_SZ + q * 8]; \
    Y_[0] = *(const float4*)(xp_ + 0);   Y_[1] = *(const float4*)(xp_ + 4); \
    Y_[2] = *(const float4*)(xp_ + 32);  Y_[3] = *(const float4*)(xp_ + 36); \
    Y_[4] = *(const float4*)(xp_ + 64);  Y_[5] = *(const float4*)(xp_ + 68); \
    Y_[6] = *(const float4*)(xp_ + 96);  Y_[7] = *(const float4*)(xp_ + 100); }

// produce gi block (16 timesteps = MFMA rows) into gil[PD_]
#define PRODUCE(PD_, Y_) { \
    f16x8 xf_[4]; \
    _Pragma("unroll") for (int kk_ = 0; kk_ < 4; kk_++) { \
      f16x8 f_; \
      f_[0] = (_Float16)Y_[2*kk_].x;   f_[1] = (_Float16)Y_[2*kk_].y; \
      f_[2] = (_Float16)Y_[2*kk_].z;   f_[3] = (_Float16)Y_[2*kk_].w; \
      f_[4] = (_Float16)Y_[2*kk_+1].x; f_[5] = (_Float16)Y_[2*kk_+1].y; \
      f_[6] = (_Float16)Y_[2*kk_+1].z; f_[7] = (_Float16)Y_[2*kk_+1].w; \
      xf_[kk_] = f_; } \
    f32x4 ac_[3][2]; \
    _Pragma("unroll") for (int g3_ = 0; g3_ < 3; g3_++) \
      _Pragma("unroll") for (int c2_ = 0; c2_ < 2; c2_++) { \
        const float bv_ = (g3_ == 2) ? 0.f : biasS[g3_][c2_]; \
        ac_[g3_][c2_] = (f32x4){bv_, bv_, bv_, bv_}; } \
    _Pragma("unroll") for (int kk_ = 0; kk_ < 4; kk_++) \
      _Pragma("unroll") for (int g3_ = 0; g3_ < 3; g3_++) \
        _Pragma("unroll") for (int c2_ = 0; c2_ < 2; c2_++) \
          ac_[g3_][c2_] = __builtin_amdgcn_mfma_f32_16x16x32_f16( \
              xf_[kk_], wiF[g3_][c2_][kk_], ac_[g3_][c2_], 0, 0, 0); \
    _Pragma("unroll") for (int c2_ = 0; c2_ < 2; c2_++) \
      _Pragma("unroll") for (int j_ = 0; j_ < 4; j_++) { \
        f16x4 pv_; \
        pv_[0] = (_Float16)ac_[0][c2_][j_]; \
        pv_[1] = (_Float16)ac_[1][c2_][j_]; \
        pv_[2] = (_Float16)ac_[2][c2_][j_]; \
        pv_[3] = (_Float16)0.f; \
        *(f16x4*)&gil[PD_][q * 4 + j_][w * 32 + c2_ * 16 + s][0] = pv_; } }

// one scan step: G_ = f16x4 {r,z,n,_} for this lane's column (consumed),
// refilled from gil[PP_] row (T_+4)&15.
#define STEPF(T_, G_, RN_, PP_) { \
    const int p_ = (T_) & 1; \
    f16x8 hf0_ = *(const f16x8*)&ht[p_][ 0 + q * 8]; \
    f16x8 hf1_ = *(const f16x8*)&ht[p_][32 + q * 8]; \
    f16x8 hf2_ = *(const f16x8*)&ht[p_][64 + q * 8]; \
    f16x8 hf3_ = *(const f16x8*)&ht[p_][96 + q * 8]; \
    const float gr_ = (float)G_[0], gz_ = (float)G_[1], gn_ = (float)G_[2]; \
    G_ = *(const f16x4*)&gil[PP_][((T_) + 4) & 15][cq][0]; \
    f32x4 aR0_ = __builtin_amdgcn_mfma_f32_16x16x32_f16(hf0_, whF[0][0][0], Z4, 0, 0, 0); \
    f32x4 aR1_ = __builtin_amdgcn_mfma_f32_16x16x32_f16(hf0_, whF[0][1][0], Z4, 0, 0, 0); \
    aR0_ = __builtin_amdgcn_mfma_f32_16x16x32_f16(hf1_, whF[0][0][1], aR0_, 0, 0, 0); \
    aR1_ = __builtin_amdgcn_mfma_f32_16x16x32_f16(hf1_, whF[0][1][1], aR1_, 0, 0, 0); \
    aR0_ = __builtin_amdgcn_mfma_f32_16x16x32_f16(hf2_, whF[0][0][2], aR0_, 0, 0, 0); \
    aR1_ = __builtin_amdgcn_mfma_f32_16x16x32_f16(hf2_, whF[0][1][2], aR1_, 0, 0, 0); \
    aR0_ = __builtin_amdgcn_mfma_f32_16x16x32_f16(hf3_, whF[0][0][3], aR0_, 0, 0, 0); \
    aR1_ = __builtin_amdgcn_mfma_f32_16x16x32_f16(hf3_, whF[0][1][3], aR1_, 0, 0, 0); \
    f32x4 aZ0_ = __builtin_amdgcn_mfma_f32_16x16x32_f16(hf0_, whF[1][0][0], Z4, 0, 0, 0); \
    f32x4 aZ1_ = __builtin_amdgcn_mfma_f32_16x16x32_f16(hf0_, whF[1][1][0], Z4, 0, 0, 0); \
    aZ0_ = __builtin_amdgcn_mfma_f32_16x16x32_f16(hf1_, whF[1][0][1], aZ0_, 0, 0, 0); \
    aZ1_ = __builtin_amdgcn_mfma_f32_16x16x32_f16(hf1_, whF[1][1][1], aZ1_, 0, 0, 0); \
    aZ0_ = __builtin_amdgcn_mfma_f32_16x16x32_f16(hf2_, whF[1][0][2], aZ0_, 0, 0, 0); \
    aZ1_ = __builtin_amdgcn_mfma_f32_16x16x32_f16(hf2_, whF[1][1][2], aZ1_, 0, 0, 0); \
    aZ0_ = __builtin_amdgcn_mfma_f32_16x16x32_f16(hf3_, whF[1][0][3], aZ0_, 0, 0, 0); \
    aZ1_ = __builtin_amdgcn_mfma_f32_16x16x32_f16(hf3_, whF[1][1][3], aZ1_, 0, 0, 0); \
    f32x4 aN0_ = __builtin_amdgcn_mfma_f32_16x16x32_f16(hf0_, whF[2][0][0], Z4, 0, 0, 0); \
    f32x4 aN1_ = __builtin_amdgcn_mfma_f32_16x16x32_f16(hf0_, whF[2][1][0], Z4, 0, 0, 0); \
    aN0_ = __builtin_amdgcn_mfma_f32_16x16x32_f16(hf1_, whF[2][0][1], aN0_, 0, 0, 0); \
    aN1_ = __builtin_amdgcn_mfma_f32_16x16x32_f16(hf1_, whF[2][1][1], aN1_, 0, 0, 0); \
    aN0_ = __builtin_amdgcn_mfma_f32_16x16x32_f16(hf2_, whF[2][0][2], aN0_, 0, 0, 0); \
    aN1_ = __builtin_amdgcn_mfma_f32_16x16x32_f16(hf2_, whF[2][1][2], aN1_, 0, 0, 0); \
    aN0_ = __builtin_amdgcn_mfma_f32_16x16x32_f16(hf3_, whF[2][0][3], aN0_, 0, 0, 0); \
    aN1_ = __builtin_amdgcn_mfma_f32_16x16x32_f16(hf3_, whF[2][1][3], aN1_, 0, 0, 0); \
    const float sR_ = (cg ? aR1_[0] : aR0_[0]) + gr_; \
    const float r_ = fastrcp(1.f + fexp2(-sR_)); \
    const float sZ_ = (cg ? aZ1_[0] : aZ0_[0]) + gz_; \
    const float z_ = fastrcp(1.f + fexp2(-sZ_)); \
    const float sN_ = (cg ? aN1_[0] : aN0_[0]) + bh_n; \
    const float e2_ = fexp2(gn_ + r_ * sN_); \
    const float n_ = 1.f - 2.f * fastrcp(e2_ + 1.f); \
    const float hnew_ = n_ + z_ * (hu - n_); \
    hu = (RN_) ? h0c : hnew_; \
    if (wrH) ht[p_ ^ 1][cq] = (_Float16)hu; \
    else ys[((size_t)(T_) * B_SZ + b) * H_SZ + cq] = hnew_; \
    yfin = hnew_; \
    BARL(); }

__global__ __launch_bounds__(256, 1)
void gru_fused(const float* __restrict__ seq,
               const int* __restrict__ resets,
               const float* __restrict__ h0,
               const float* __restrict__ Wi,
               const float* __restrict__ Wh,
               const float* __restrict__ bh,
               float* __restrict__ out) {
  const int b = blockIdx.x;
  const int tid = threadIdx.x;
  const int w = tid >> 6;          // wave 0..3: cols [w*32, w*32+32)
  const int lane = tid & 63;
  const int q = lane >> 4;         // A k-group / C row-group / role
  const int s = lane & 15;         // A row (timestep in produce) / B,C col
  const int cg = q >> 1;           // which 16-col tile this lane owns
  const int cq = w * 32 + (cg << 4) + s;  // this lane's hidden column
  const bool wrH = ((q & 1) == 0); // role: ht writeback vs ys store

  __shared__ int rsts[T_STEPS];                        // 4 KB, SHIFTED by 1
  __shared__ __align__(16) _Float16 ht[2][H_SZ];       // 512 B
  __shared__ __align__(16) _Float16 gil[2][16][132][4];// 33 KB, {r,z,n,_}

  for (int i = tid; i < T_STEPS; i += 256)
    rsts[i] = (i < T_STEPS - 1) ? resets[(size_t)(i + 1) * B_SZ + b] : 0;

  // weight B-frags (pre-scaled): gate g3, coltile c2 -> col g3*128 + w*32 +
  // c2*16 + s; k = kk*32 + q*8 + e.  whF: scan (Wh), wiF: produce (Wi).
  f16x8 whF[3][2][4], wiF[3][2][4];
  float biasS[2][2];
#pragma unroll
  for (int g3 = 0; g3 < 3; g3++) {
    const float sc = (g3 == 2) ? SC_N : SC_RZ;
#pragma unroll
    for (int c2 = 0; c2 < 2; c2++) {
      const int col = g3 * H_SZ + w * 32 + c2 * 16 + s;
      if (g3 < 2) biasS[g3][c2] = SC_RZ * bh[col];
#pragma unroll
      for (int kk = 0; kk < 4; kk++) {
        f16x8 fh, fi;
#pragma unroll
        for (int e = 0; e < 8; e++) {
          const size_t ko = (size_t)(kk * 32 + q * 8 + e) * 384 + col;
          fh[e] = (_Float16)(sc * Wh[ko]);
          fi[e] = (_Float16)(sc * Wi[ko]);
        }
        whF[g3][c2][kk] = fh;
        wiF[g3][c2][kk] = fi;
      }
    }
  }

  const f32x4 Z4 = {0.f, 0.f, 0.f, 0.f};
  const float bh_n = SC_N * bh[2 * H_SZ + cq];
  const float h0c = h0[(size_t)b * H_SZ + cq];
  float hu = h0c;
  float yfin = h0c;

  if (tid < H_SZ) ht[0][tid] = (_Float16)h0[(size_t)b * H_SZ + tid];

  // prologue: produce gi for steps 0..15 into gil[0]; stage x for 16..31
  float4 ya[8];
  LOADX(0, ya)
  PRODUCE(0, ya)
  LOADX(16, ya)
  __syncthreads();

  f16x4 gA = *(const f16x4*)&gil[0][0][cq][0];
  f16x4 gB = *(const f16x4*)&gil[0][1][cq][0];
  f16x4 gC = *(const f16x4*)&gil[0][2][cq][0];
  f16x4 gD = *(const f16x4*)&gil[0][3][cq][0];

  float* ys = out + (size_t)B_SZ * H_SZ;  // out = [final_carry] ++ [ys]

#pragma unroll 1
  for (int T0 = 0; T0 < T_STEPS; T0 += 16) {
    const int par = (T0 >> 4) & 1;
    const int parx = par ^ 1;
    PRODUCE(parx, ya)          // gi for steps T0+16..T0+31 (barrier-covered)
    LOADX(T0 + 32, ya)         // x for the next produce (16-step lead)
    const int4 r0 = *(const int4*)&rsts[T0];
    const int4 r1 = *(const int4*)&rsts[T0 + 4];
    const int4 r2 = *(const int4*)&rsts[T0 + 8];
    const int4 r3 = *(const int4*)&rsts[T0 + 12];
    STEPF(T0 + 0,  gA, r0.x, par)
    STEPF(T0 + 1,  gB, r0.y, par)
    STEPF(T0 + 2,  gC, r0.z, par)
    STEPF(T0 + 3,  gD, r0.w, par)
    STEPF(T0 + 4,  gA, r1.x, par)
    STEPF(T0 + 5,  gB, r1.y, par)
    STEPF(T0 + 6,  gC, r1.z, par)
    STEPF(T0 + 7,  gD, r1.w, par)
    STEPF(T0 + 8,  gA, r2.x, par)
    STEPF(T0 + 9,  gB, r2.y, par)
    STEPF(T0 + 10, gC, r2.z, par)
    STEPF(T0 + 11, gD, r2.w, par)
    STEPF(T0 + 12, gA, r3.x, parx)   // prefetch rows 0..3 of next buffer
    STEPF(T0 + 13, gB, r3.y, parx)
    STEPF(T0 + 14, gC, r3.z, parx)
    STEPF(T0 + 15, gD, r3.w, parx)
  }
  if (wrH) out[(size_t)b * H_SZ + cq] = yfin;  // final carry = hnew(1023)
}

extern "C" void kernel_launch(void* const* d_in, const int* in_sizes, int n_in,
                              void* d_out, int out_size, void* d_ws, size_t ws_size,
                              hipStream_t stream) {
  const float* seq    = (const float*)d_in[0];
  const int*   resets = (const int*)d_in[1];
  const float* h0     = (const float*)d_in[2];
  const float* Wi     = (const float*)d_in[3];
  const float* Wh     = (const float*)d_in[4];
  const float* bh     = (const float*)d_in[5];
  (void)in_sizes; (void)n_in; (void)out_size; (void)d_ws; (void)ws_size;

  gru_fused<<<B_SZ, 256, 0, stream>>>(seq, resets, h0, Wi, Wh, bh,
                                      (float*)d_out);
}